// Round 1
// baseline (2879.842 us; speedup 1.0000x reference)
//
#include <hip/hip_runtime.h>
#include <hip/hip_bf16.h>
#include <stdint.h>

#define H 1024
#define BATCH 64
#define TSTEPS 64
#define VOCAB 32000

typedef __attribute__((ext_vector_type(8))) short bf16x8;
typedef __attribute__((ext_vector_type(4))) float f32x4;

__device__ __forceinline__ uint16_t f2b(float f) {
  union { float f; uint32_t u; } v; v.f = f;
  uint32_t u = v.u;
  return (uint16_t)((u + 0x7FFFu + ((u >> 16) & 1u)) >> 16);
}

__device__ __forceinline__ void g2l16(const uint16_t* g, uint16_t* l) {
  __builtin_amdgcn_global_load_lds((const __attribute__((address_space(1))) void*)(g),
                                   (__attribute__((address_space(3))) void*)(l), 16, 0, 0);
}

// ---- f32 -> bf16 cast (n4 = n/4) ----
__global__ void cast_bf16_kernel(const float* __restrict__ src, uint16_t* __restrict__ dst, int n4) {
  int i = blockIdx.x * blockDim.x + threadIdx.x;
  int stride = gridDim.x * blockDim.x;
  for (; i < n4; i += stride) {
    float4 f = ((const float4*)src)[i];
    union { uint16_t u[4]; uint64_t d; } o;
    o.u[0] = f2b(f.x); o.u[1] = f2b(f.y); o.u[2] = f2b(f.z); o.u[3] = f2b(f.w);
    ((uint64_t*)dst)[i] = o.d;
  }
}

// ---- embed + relu -> bf16, X[t*64+b][H] ----
__global__ void embed_kernel(const float* __restrict__ emb, const int* __restrict__ tgt,
                             uint16_t* __restrict__ X) {
  int i = blockIdx.x;            // 0..4095 = t*64+b
  int t = i >> 6, b = i & 63;
  int tok = (t == 0) ? 0 : tgt[b * TSTEPS + (t - 1)];
  const float4* src = (const float4*)(emb + (size_t)tok * H);
  uint64_t* dst = (uint64_t*)(X + (size_t)i * H);
  int k = threadIdx.x;           // 256 threads x 4 elems
  float4 f = src[k];
  union { uint16_t u[4]; uint64_t d; } o;
  o.u[0] = f2b(fmaxf(f.x, 0.f)); o.u[1] = f2b(fmaxf(f.y, 0.f));
  o.u[2] = f2b(fmaxf(f.z, 0.f)); o.u[3] = f2b(fmaxf(f.w, 0.f));
  dst[k] = o.d;
}

// ---- h0 init: copy f32 + cast bf16 ----
__global__ void h0_kernel(const float* __restrict__ eh, float* __restrict__ h0,
                          uint16_t* __restrict__ hb0) {
  int i = blockIdx.x * blockDim.x + threadIdx.x;   // 16384 threads x 4
  float4 f = ((const float4*)eh)[i];
  ((float4*)h0)[i] = f;
  union { uint16_t u[4]; uint64_t d; } o;
  o.u[0] = f2b(f.x); o.u[1] = f2b(f.y); o.u[2] = f2b(f.z); o.u[3] = f2b(f.w);
  ((uint64_t*)hb0)[i] = o.d;
}

// ---- one GRU step: gi + gh MFMA fused, gates, h update ----
// grid 64 blocks (16 H-cols each), 256 threads (4 waves = 4 m-slices of 16)
__global__ __launch_bounds__(256) void step_kernel(
    const uint16_t* __restrict__ Xb,      // [4096][H] bf16
    const uint16_t* __restrict__ Wih,     // [3H][H] bf16
    const uint16_t* __restrict__ Whh,     // [3H][H] bf16
    const float* __restrict__ b_ih,       // [3H]
    const float* __restrict__ b_hh,       // [3H]
    const float* __restrict__ h_cur,      // [64][H] f32
    const uint16_t* __restrict__ hb_cur,  // [64][H] bf16
    float* __restrict__ h_nxt,
    uint16_t* __restrict__ hb_nxt,
    uint16_t* __restrict__ Hs,            // [4096][H] bf16 history
    int t) {
  const int tid = threadIdx.x;
  const int lane = tid & 63;
  const int w = tid >> 6;
  const int c0 = blockIdx.x * 16;
  const int l15 = lane & 15;
  const int kq = lane >> 4;     // 0..3
  const int mrow0 = w * 16;

  f32x4 acc_i[3] = {{0,0,0,0},{0,0,0,0},{0,0,0,0}};
  f32x4 acc_h[3] = {{0,0,0,0},{0,0,0,0},{0,0,0,0}};

  const uint16_t* xptr = Xb + (size_t)(t * BATCH + mrow0 + l15) * H + kq * 8;
  const uint16_t* hptr = hb_cur + (size_t)(mrow0 + l15) * H + kq * 8;
  const uint16_t* wi0 = Wih + (size_t)(c0 + l15) * H + kq * 8;
  const uint16_t* wh0 = Whh + (size_t)(c0 + l15) * H + kq * 8;

  for (int kk = 0; kk < H; kk += 32) {
    bf16x8 ai = *(const bf16x8*)(xptr + kk);
    bf16x8 ah = *(const bf16x8*)(hptr + kk);
#pragma unroll
    for (int g = 0; g < 3; ++g) {
      bf16x8 bi = *(const bf16x8*)(wi0 + (size_t)g * 1024 * H + kk);
      bf16x8 bh = *(const bf16x8*)(wh0 + (size_t)g * 1024 * H + kk);
      acc_i[g] = __builtin_amdgcn_mfma_f32_16x16x32_bf16(ai, bi, acc_i[g], 0, 0, 0);
      acc_h[g] = __builtin_amdgcn_mfma_f32_16x16x32_bf16(ah, bh, acc_h[g], 0, 0, 0);
    }
  }

  int j = c0 + l15;
  float bir = b_ih[j],        bhr = b_hh[j];
  float biz = b_ih[1024 + j], bhz = b_hh[1024 + j];
  float bin = b_ih[2048 + j], bhn = b_hh[2048 + j];
#pragma unroll
  for (int r = 0; r < 4; ++r) {
    int m = mrow0 + kq * 4 + r;
    float ir = acc_i[0][r] + bir, hr = acc_h[0][r] + bhr;
    float iz = acc_i[1][r] + biz, hz = acc_h[1][r] + bhz;
    float in_ = acc_i[2][r] + bin, hn = acc_h[2][r] + bhn;
    float rg = 1.f / (1.f + expf(-(ir + hr)));
    float zg = 1.f / (1.f + expf(-(iz + hz)));
    float ng = tanhf(in_ + rg * hn);
    float hold = h_cur[(size_t)m * H + j];
    float hnew = (1.f - zg) * ng + zg * hold;
    h_nxt[(size_t)m * H + j] = hnew;
    uint16_t hb = f2b(hnew);
    hb_nxt[(size_t)m * H + j] = hb;
    Hs[(size_t)(t * BATCH + m) * H + j] = hb;
  }
}

// ---- big output GEMM: logits = Hs @ Wout^T + b, written to d_out[b][t][v] ----
// 128x128 tile, BK=32, 4 waves 2x2, global_load_lds staging (m97 structure)
__global__ __launch_bounds__(256) void out_gemm_kernel(
    const uint16_t* __restrict__ A,    // [4096][1024]
    const uint16_t* __restrict__ Bm,   // [32000][1024]
    const float* __restrict__ bias,    // [32000]
    float* __restrict__ out) {
  __shared__ uint16_t lA[128 * 32];
  __shared__ uint16_t lB[128 * 32];
  const int tid = threadIdx.x;
  const int lane = tid & 63;
  const int w = tid >> 6;
  const int wr = w >> 1, wc = w & 1;
  const int m0 = blockIdx.y * 128;
  const int n0 = blockIdx.x * 128;

  f32x4 acc[4][4];
#pragma unroll
  for (int mi = 0; mi < 4; ++mi)
#pragma unroll
    for (int ni = 0; ni < 4; ++ni) acc[mi][ni] = (f32x4){0, 0, 0, 0};

  const int srow = w * 16 + (lane >> 2);
  const int scol = (lane & 3) * 8;

  for (int k0 = 0; k0 < 1024; k0 += 32) {
    __syncthreads();
    g2l16(A + (size_t)(m0 + srow) * 1024 + k0 + scol,       &lA[w * 512]);
    g2l16(A + (size_t)(m0 + 64 + srow) * 1024 + k0 + scol,  &lA[2048 + w * 512]);
    g2l16(Bm + (size_t)(n0 + srow) * 1024 + k0 + scol,      &lB[w * 512]);
    g2l16(Bm + (size_t)(n0 + 64 + srow) * 1024 + k0 + scol, &lB[2048 + w * 512]);
    __syncthreads();
    bf16x8 a[4], b[4];
#pragma unroll
    for (int mi = 0; mi < 4; ++mi)
      a[mi] = *(const bf16x8*)&lA[(wr * 64 + mi * 16 + (lane & 15)) * 32 + (lane >> 4) * 8];
#pragma unroll
    for (int ni = 0; ni < 4; ++ni)
      b[ni] = *(const bf16x8*)&lB[(wc * 64 + ni * 16 + (lane & 15)) * 32 + (lane >> 4) * 8];
#pragma unroll
    for (int mi = 0; mi < 4; ++mi)
#pragma unroll
      for (int ni = 0; ni < 4; ++ni)
        acc[mi][ni] = __builtin_amdgcn_mfma_f32_16x16x32_bf16(a[mi], b[ni], acc[mi][ni], 0, 0, 0);
  }

#pragma unroll
  for (int ni = 0; ni < 4; ++ni) {
    int v = n0 + wc * 64 + ni * 16 + (lane & 15);
    float bv = bias[v];
#pragma unroll
    for (int mi = 0; mi < 4; ++mi) {
#pragma unroll
      for (int r = 0; r < 4; ++r) {
        int row = m0 + wr * 64 + mi * 16 + (lane >> 4) * 4 + r;  // row = t*64+b
        size_t off = (size_t)(row & 63) * (TSTEPS * (size_t)VOCAB)
                   + (size_t)(row >> 6) * VOCAB + v;
        out[off] = acc[mi][ni][r] + bv;
      }
    }
  }
}

// ---- in-place log_softmax over rows of 32000 ----
__global__ __launch_bounds__(256) void lsm_kernel(float* __restrict__ out) {
  float* row = out + (size_t)blockIdx.x * VOCAB;
  const int tid = threadIdx.x;
  float m = -3.4e38f, s = 0.f;
  for (int i = tid * 4; i < VOCAB; i += 1024) {
    float4 x = *(const float4*)(row + i);
    float lm = fmaxf(fmaxf(x.x, x.y), fmaxf(x.z, x.w));
    if (lm > m) { s *= expf(m - lm); m = lm; }
    s += expf(x.x - m) + expf(x.y - m) + expf(x.z - m) + expf(x.w - m);
  }
#pragma unroll
  for (int off = 32; off > 0; off >>= 1) {
    float m2 = __shfl_xor(m, off);
    float s2 = __shfl_xor(s, off);
    float mn = fmaxf(m, m2);
    s = s * expf(m - mn) + s2 * expf(m2 - mn);
    m = mn;
  }
  __shared__ float sm[4], ss[4];
  if ((tid & 63) == 0) { sm[tid >> 6] = m; ss[tid >> 6] = s; }
  __syncthreads();
  float M = fmaxf(fmaxf(sm[0], sm[1]), fmaxf(sm[2], sm[3]));
  float S = ss[0] * expf(sm[0] - M) + ss[1] * expf(sm[1] - M)
          + ss[2] * expf(sm[2] - M) + ss[3] * expf(sm[3] - M);
  float lse = M + logf(S);
  for (int i = tid * 4; i < VOCAB; i += 1024) {
    float4 x = *(const float4*)(row + i);
    x.x -= lse; x.y -= lse; x.z -= lse; x.w -= lse;
    *(float4*)(row + i) = x;
  }
}

__global__ void hcopy_kernel(const float* __restrict__ h, float* __restrict__ out) {
  int i = blockIdx.x * blockDim.x + threadIdx.x;
  ((float4*)out)[i] = ((const float4*)h)[i];
}

extern "C" void kernel_launch(void* const* d_in, const int* in_sizes, int n_in,
                              void* d_out, int out_size, void* d_ws, size_t ws_size,
                              hipStream_t stream) {
  const float* enc_hidden = (const float*)d_in[1];   // [1,64,1024]
  const int* tgt          = (const int*)d_in[2];     // [64,64]
  const float* emb        = (const float*)d_in[3];   // [32000,1024]
  const float* W_ih       = (const float*)d_in[4];   // [3072,1024]
  const float* W_hh       = (const float*)d_in[5];   // [3072,1024]
  const float* b_ih       = (const float*)d_in[6];   // [3072]
  const float* b_hh       = (const float*)d_in[7];   // [3072]
  const float* W_out      = (const float*)d_in[8];   // [32000,1024]
  const float* b_out      = (const float*)d_in[9];   // [32000]
  float* out = (float*)d_out;

  char* ws = (char*)d_ws;
  uint16_t* Wih_b  = (uint16_t*)(ws);                 // 6,291,456 B
  uint16_t* Whh_b  = (uint16_t*)(ws + 6291456);       // 6,291,456 B
  uint16_t* Wout_b = (uint16_t*)(ws + 12582912);      // 65,536,000 B
  uint16_t* Xb     = (uint16_t*)(ws + 78118912);      // 8,388,608 B
  uint16_t* Hs     = (uint16_t*)(ws + 86507520);      // 8,388,608 B
  float*    hbuf0  = (float*)   (ws + 94896128);      // 262,144 B
  float*    hbuf1  = (float*)   (ws + 95158272);      // 262,144 B
  uint16_t* hb0    = (uint16_t*)(ws + 95420416);      // 131,072 B
  uint16_t* hb1    = (uint16_t*)(ws + 95551488);      // 131,072 B  (total ~95.7 MB)

  cast_bf16_kernel<<<2048, 256, 0, stream>>>(W_ih, Wih_b, 3072 * 1024 / 4);
  cast_bf16_kernel<<<2048, 256, 0, stream>>>(W_hh, Whh_b, 3072 * 1024 / 4);
  cast_bf16_kernel<<<2048, 256, 0, stream>>>(W_out, Wout_b, VOCAB * 1024 / 4);
  embed_kernel<<<4096, 256, 0, stream>>>(emb, tgt, Xb);
  h0_kernel<<<64, 256, 0, stream>>>(enc_hidden, hbuf0, hb0);

  for (int t = 0; t < TSTEPS; ++t) {
    const float* hc = (t & 1) ? hbuf1 : hbuf0;
    float* hn       = (t & 1) ? hbuf0 : hbuf1;
    const uint16_t* hbc = (t & 1) ? hb1 : hb0;
    uint16_t* hbn       = (t & 1) ? hb0 : hb1;
    step_kernel<<<64, 256, 0, stream>>>(Xb, Wih_b, Whh_b, b_ih, b_hh,
                                        hc, hbc, hn, hbn, Hs, t);
  }

  dim3 g(250, 32);
  out_gemm_kernel<<<g, 256, 0, stream>>>(Hs, Wout_b, b_out, out);
  lsm_kernel<<<4096, 256, 0, stream>>>(out);
  hcopy_kernel<<<64, 256, 0, stream>>>(hbuf0, out + 131072000ull);
}